// Round 18
// baseline (834.075 us; speedup 1.0000x reference)
//
#include <hip/hip_runtime.h>
#include <hip/hip_bf16.h>
#include <hip/hip_fp8.h>
#include <cstdint>

// TripCenterLoss_min_margin: B=8192, C=4096, D=2048
// loss = mean_b max(margin + w*dist_own(b) - (1-w)*min_{c!=lbl} dist(b,c), 0)
constexpr int NB = 8192;
constexpr int NC = 4096;
constexpr int ND = 2048;

// ---- fp8 32x32x64 GEMM, cross-tile REGISTER double-buffered pipeline ----
constexpr int BM = 256, BN = 256, BK = 64;
constexpr int NRB = NB / BM;    // 32
constexpr int NCB = NC / BN;    // 16
constexpr int NWG = NRB * NCB;  // 512  (%8==0 -> bijective XCD swizzle)
constexpr int NT = ND / BK;     // 32 K-tiles
constexpr int NSLOT = NC / 64;  // 64 pmin slots per row

typedef __attribute__((ext_vector_type(8))) __bf16 bf16x8;
typedef __attribute__((ext_vector_type(8))) unsigned short usvec8;
typedef __attribute__((ext_vector_type(4))) unsigned short usvec4;
typedef __attribute__((ext_vector_type(4))) float f32x4;
typedef __attribute__((ext_vector_type(16))) float f32x16;
typedef __attribute__((ext_vector_type(4))) int i32x4;
typedef __attribute__((ext_vector_type(8))) int i32x8;

__device__ inline unsigned short f2bf(float f) {
  unsigned int u = __float_as_uint(f);
  u += 0x7fffu + ((u >> 16) & 1u);  // RNE
  return (unsigned short)(u >> 16);
}

__device__ inline unsigned char f2fp8(float f) {
  return (unsigned char)__hip_cvt_float_to_fp8(f, __HIP_SATFINITE, __HIP_E4M3);
}

// ---------------- fused norms + f32->fp8(e4m3) convert ----------------
__global__ __launch_bounds__(256) void prep_kernel(const float* __restrict__ x,
                                                   const float* __restrict__ cen,
                                                   float* __restrict__ xnorm,
                                                   float* __restrict__ cnorm,
                                                   unsigned char* __restrict__ xb,
                                                   unsigned char* __restrict__ cb) {
  int row = blockIdx.x;
  const float* src;
  float* ndst;
  unsigned char* bdst;
  if (row < NB) { src = x + (size_t)row * ND; ndst = xnorm + row; bdst = xb + (size_t)row * ND; }
  else { row -= NB; src = cen + (size_t)row * ND; ndst = cnorm + row; bdst = cb + (size_t)row * ND; }
  float s = 0.f;
  #pragma unroll
  for (int it = 0; it < 2; it++) {
    int i = threadIdx.x * 4 + it * 1024;
    float4 v = *(const float4*)(src + i);
    s += v.x * v.x + v.y * v.y + v.z * v.z + v.w * v.w;
    unsigned p = (unsigned)f2fp8(v.x) | ((unsigned)f2fp8(v.y) << 8) |
                 ((unsigned)f2fp8(v.z) << 16) | ((unsigned)f2fp8(v.w) << 24);
    *(unsigned*)(bdst + i) = p;
  }
  #pragma unroll
  for (int m = 1; m < 64; m <<= 1) s += __shfl_xor(s, m);
  __shared__ float red[4];
  int lane = threadIdx.x & 63, wid = threadIdx.x >> 6;
  if (lane == 0) red[wid] = s;
  __syncthreads();
  if (threadIdx.x == 0) *ndst = red[0] + red[1] + red[2] + red[3];
}

// ---------------- norms only (fallback path) ----------------
__global__ __launch_bounds__(256) void norms_kernel(const float* __restrict__ x,
                                                    const float* __restrict__ cen,
                                                    float* __restrict__ xnorm,
                                                    float* __restrict__ cnorm) {
  int row = blockIdx.x;
  const float* src;
  float* dst;
  if (row < NB) { src = x + (size_t)row * ND; dst = xnorm + row; }
  else          { src = cen + (size_t)(row - NB) * ND; dst = cnorm + (row - NB); }
  float s = 0.f;
  #pragma unroll
  for (int it = 0; it < 2; it++) {
    int i = threadIdx.x * 4 + it * 1024;
    float4 v = *(const float4*)(src + i);
    s += v.x * v.x + v.y * v.y + v.z * v.z + v.w * v.w;
  }
  #pragma unroll
  for (int m = 1; m < 64; m <<= 1) s += __shfl_xor(s, m);
  __shared__ float red[4];
  int lane = threadIdx.x & 63, wid = threadIdx.x >> 6;
  if (lane == 0) red[wid] = s;
  __syncthreads();
  if (threadIdx.x == 0) *dst = red[0] + red[1] + red[2] + red[3];
}

// ---------------- async global->LDS ----------------
__device__ inline void gload_lds16(const void* g, void* lds) {
  __builtin_amdgcn_global_load_lds(
      (const __attribute__((address_space(1))) unsigned int*)g,
      (__attribute__((address_space(3))) unsigned int*)lds, 16, 0, 0);
}

// ---------------- fp8 32x32x64 fused GEMM, register-pipelined ----------------
// Layout/swizzle/epilogue = R15 (passed, absmax 0.0): 4 rotating regions
// x {A 16KB, B 16KB} = 128 KiB; swizzle pc = kc ^ ((row>>1)&3) (involution
// on global src, linear LDS dest); read un-swizzles with the same XOR.
// MFMA mfma_scale_f32_32x32x64_f8f6f4, uniform scales 0x7F; C/D layout
// col=lane&31, row=(reg&3)+8*(reg>>2)+4*(lane>>5).
//
// NEW: cross-tile REGISTER double-buffer. Iter t:
//   s_barrier            // tile t globally present (see invariant below)
//   stage(t+2)           // region (t+2)&3; its old content (t-2) was read at
//                        // iter t-2, retired by MFMA(t-2)'s lgkm at t-1,
//                        // TWO barriers before this DMA -> WAR-safe
//   vmcnt(4)             // leaves only stage(t+2) outstanding -> drains MY
//                        // stage(t+1); with the t+1-top barrier this gives the
//                        // invariant "tile t present at iter t top" for all t
//   read frags(t) -> set(t&1)        (plain C++ ds_reads, NO fence)
//   MFMA frags(t-1) from set((t-1)&1)  <- no dependence on the new reads:
//                        they drain on the LDS pipe UNDER this MFMA cluster;
//                        their lgkm wait lands at iter t+1 (a full tile away).
// Registers: acc 128 + 2 frag sets (4+2)x8x2 = 96 -> fits 256/wave (R6's bf16
// spill does not apply at this shape). Sets are NAMED (fa0/fb0, fa1/fb1),
// loop unrolled x2 + peeled tails -> all indexing compile-time (rule 20).
__global__ __launch_bounds__(512, 2) void gemm_fp8_kernel(
    const unsigned char* __restrict__ xb, const unsigned char* __restrict__ cb,
    const float* __restrict__ xnorm, const float* __restrict__ cnorm,
    const int* __restrict__ labels,
    float* __restrict__ own, float* __restrict__ pmin) {
  __shared__ unsigned char lds[4][2][256 * 64];  // 128 KiB

  const int tid = threadIdx.x;
  const int lane = tid & 63;
  const int wid = tid >> 6;
  const int llo32 = lane & 31;
  const int lhi = lane >> 5;

  int bid = blockIdx.x;
  int swz = (bid & 7) * (NWG / 8) + (bid >> 3);
  const int brow0 = (swz / NCB) * BM;
  const int bcol0 = (swz % NCB) * BN;
  const int wr = wid >> 2, wc = wid & 3;  // 2x4 wave grid: wave output 128x64

  // read-side un-swizzle: phys = logical ^ ((row>>1)&3), row = llo32
  const int rx = (llo32 >> 1) & 3;
  const int c0 = ((2 * lhi + 0) ^ rx) * 16;
  const int c1 = ((2 * lhi + 1) ^ rx) * 16;

  f32x16 acc[4][2];
  #pragma unroll
  for (int m = 0; m < 4; m++)
    #pragma unroll
    for (int n = 0; n < 2; n++)
      acc[m][n] = (f32x16)(0.f);

  // hoisted per-thread stage pointers (advance +BK per staged tile)
  const unsigned char* pga[2];
  const unsigned char* pgb[2];
  unsigned offc[2];
  #pragma unroll
  for (int i = 0; i < 2; i++) {
    int c = (wid * 2 + i) * 64 + lane;   // chunk 0..1023
    int row = c >> 2;                    // 4 chunks (64B) per row
    int kc = (c & 3) ^ ((row >> 1) & 3);
    pga[i] = xb + (size_t)(brow0 + row) * ND + kc * 16;
    pgb[i] = cb + (size_t)(bcol0 + row) * ND + kc * 16;
    offc[i] = (unsigned)c * 16u;
  }
  auto stage_tile = [&](int reg) {  // 4 gloads/thread
    #pragma unroll
    for (int i = 0; i < 2; i++) {
      gload_lds16(pga[i], &lds[reg][0][0] + offc[i]);
      gload_lds16(pgb[i], &lds[reg][1][0] + offc[i]);
    }
    #pragma unroll
    for (int i = 0; i < 2; i++) { pga[i] += BK; pgb[i] += BK; }
  };

  auto load8 = [&](const unsigned char* p) {
    i32x4 lo = *(const i32x4*)(p + c0);
    i32x4 hi = *(const i32x4*)(p + c1);
    return (i32x8){lo[0], lo[1], lo[2], lo[3], hi[0], hi[1], hi[2], hi[3]};
  };

  i32x8 fa0[4], fb0[2], fa1[4], fb1[2];

#define RDA(DST, REG)                                                          \
  _Pragma("unroll") for (int m = 0; m < 4; m++)                                \
      DST[m] = load8(&lds[REG][0][0] + (wr * 128 + m * 32 + llo32) * 64);
#define RDB(DST, REG)                                                          \
  _Pragma("unroll") for (int n = 0; n < 2; n++)                                \
      DST[n] = load8(&lds[REG][1][0] + (wc * 64 + n * 32 + llo32) * 64);
#define MFMA8(FA, FB)                                                          \
  __builtin_amdgcn_s_setprio(1);                                               \
  _Pragma("unroll") for (int m = 0; m < 4; m++)                                \
    _Pragma("unroll") for (int n = 0; n < 2; n++)                              \
      acc[m][n] = __builtin_amdgcn_mfma_scale_f32_32x32x64_f8f6f4(             \
          FA[m], FB[n], acc[m][n], 0, 0, 0, 0x7F, 0, 0x7F);                    \
  __builtin_amdgcn_s_setprio(0);

  // prologue: tiles 0,1 staged; drain 0 (mine) then barrier -> 0 global
  stage_tile(0);
  stage_tile(1);
  asm volatile("s_waitcnt vmcnt(4)" ::: "memory");
  __builtin_amdgcn_s_barrier();
  // iter 0 (read-only): stage 2, drain 1, read frags(0) -> set0
  stage_tile(2);
  asm volatile("s_waitcnt vmcnt(4)" ::: "memory");
  RDA(fa0, 0); RDB(fb0, 0);

  // pairs p=0..13 cover t=1..28
  for (int p = 0; p < 14; ++p) {
    const int t1 = 2 * p + 1, t2 = 2 * p + 2;
    const int r1 = t1 & 3, r2 = t2 & 3;
    // t1 (odd): read set1, MFMA set0 (frags t1-1)
    __builtin_amdgcn_s_barrier();
    stage_tile((t1 + 2) & 3);
    asm volatile("s_waitcnt vmcnt(4)" ::: "memory");
    RDA(fa1, r1); RDB(fb1, r1);
    MFMA8(fa0, fb0);
    // t2 (even): read set0, MFMA set1
    __builtin_amdgcn_s_barrier();
    stage_tile((t2 + 2) & 3);
    asm volatile("s_waitcnt vmcnt(4)" ::: "memory");
    RDA(fa0, r2); RDB(fb0, r2);
    MFMA8(fa1, fb1);
  }
  // t=29: stage tile 31 (last), read frags29 -> set1, MFMA frags28
  __builtin_amdgcn_s_barrier();
  stage_tile(3);  // tile 31 -> region 3
  asm volatile("s_waitcnt vmcnt(4)" ::: "memory");
  RDA(fa1, 1); RDB(fb1, 1);
  MFMA8(fa0, fb0);
  // t=30: no stage; drain tile 31; read frags30 -> set0, MFMA frags29
  __builtin_amdgcn_s_barrier();
  asm volatile("s_waitcnt vmcnt(0)" ::: "memory");
  RDA(fa0, 2); RDB(fb0, 2);
  MFMA8(fa1, fb1);
  // t=31: read frags31 -> set1, MFMA frags30
  __builtin_amdgcn_s_barrier();
  RDA(fa1, 3); RDB(fb1, 3);
  MFMA8(fa0, fb0);
  // final: MFMA frags31 (compiler inserts the lgkm wait)
  MFMA8(fa1, fb1);

  // ---- epilogue: dist = xn + cn - 2*dot; own-col; per-row min ----
  // 32x32 C/D layout (R15-verified): col = lane&31,
  // row = (reg&3) + 8*(reg>>2) + 4*(lane>>5), reg in [0,16)
  const int col0 = bcol0 + wc * 64 + llo32;
  const int col1 = col0 + 32;
  const float cn0 = cnorm[col0];
  const float cn1 = cnorm[col1];
  const int cslot = bcol0 / 64 + wc;
  #pragma unroll
  for (int m = 0; m < 4; m++) {
    #pragma unroll
    for (int g = 0; g < 4; g++) {
      const int r0 = brow0 + wr * 128 + m * 32 + lhi * 4 + g * 8;
      float4 xn4 = *(const float4*)(xnorm + r0);
      int4 lb4 = *(const int4*)(labels + r0);
      #pragma unroll
      for (int j = 0; j < 4; j++) {
        const int reg = g * 4 + j;
        const int row = r0 + j;
        const float xnv = (j == 0) ? xn4.x : (j == 1) ? xn4.y : (j == 2) ? xn4.z : xn4.w;
        const int lbl = (j == 0) ? lb4.x : (j == 1) ? lb4.y : (j == 2) ? lb4.z : lb4.w;
        float d0 = xnv + cn0 - 2.0f * acc[m][0][reg];
        float d1 = xnv + cn1 - 2.0f * acc[m][1][reg];
        float rmin = 1e38f;
        if (col0 == lbl) own[row] = d0; else rmin = d0;
        if (col1 == lbl) own[row] = d1; else rmin = fminf(rmin, d1);
        rmin = fminf(rmin, __shfl_xor(rmin, 1));
        rmin = fminf(rmin, __shfl_xor(rmin, 2));
        rmin = fminf(rmin, __shfl_xor(rmin, 4));
        rmin = fminf(rmin, __shfl_xor(rmin, 8));
        rmin = fminf(rmin, __shfl_xor(rmin, 16));
        if (llo32 == 0) pmin[(size_t)row * NSLOT + cslot] = rmin;
      }
    }
  }
#undef RDA
#undef RDB
#undef MFMA8
}

// ---------------- fallback: reg-staged 128^2 fused GEMM (small ws) ----------------
constexpr int FBM = 128, FBK = 32;
constexpr int FNWG = (NB / FBM) * (NC / FBM);
__global__ __launch_bounds__(256) void gemm_fb_kernel(
    const float* __restrict__ xf, const float* __restrict__ cf,
    const float* __restrict__ xnorm, const float* __restrict__ cnorm,
    const int* __restrict__ labels,
    float* __restrict__ own, float* __restrict__ pmin) {
  __shared__ alignas(16) unsigned short lA[FBM * FBK];
  __shared__ alignas(16) unsigned short lB[FBM * FBK];
  const int tid = threadIdx.x, lane = tid & 63, wid = tid >> 6;
  int bid = blockIdx.x;
  int swz = (bid & 7) * (FNWG >> 3) + (bid >> 3);
  const int brow0 = (swz / (NC / FBM)) * FBM;
  const int bcol0 = (swz % (NC / FBM)) * FBM;
  const int wr = wid >> 1, wc = wid & 1;
  f32x4 acc[4][4];
  #pragma unroll
  for (int m = 0; m < 4; m++)
    #pragma unroll
    for (int n = 0; n < 4; n++) acc[m][n] = (f32x4){0.f, 0.f, 0.f, 0.f};
  for (int k0 = 0; k0 < ND; k0 += FBK) {
    __syncthreads();
    int ar = tid >> 1, ac = (tid & 1) << 4;
    const float* ga = xf + (size_t)(brow0 + ar) * ND + k0 + ac;
    const float* gb = cf + (size_t)(bcol0 + ar) * ND + k0 + ac;
    usvec8 ua[2], ub[2];
    #pragma unroll
    for (int h = 0; h < 2; h++) {
      float4 p = *(const float4*)(ga + h * 8), q = *(const float4*)(ga + h * 8 + 4);
      ua[h][0] = f2bf(p.x); ua[h][1] = f2bf(p.y); ua[h][2] = f2bf(p.z); ua[h][3] = f2bf(p.w);
      ua[h][4] = f2bf(q.x); ua[h][5] = f2bf(q.y); ua[h][6] = f2bf(q.z); ua[h][7] = f2bf(q.w);
      float4 r = *(const float4*)(gb + h * 8), s = *(const float4*)(gb + h * 8 + 4);
      ub[h][0] = f2bf(r.x); ub[h][1] = f2bf(r.y); ub[h][2] = f2bf(r.z); ub[h][3] = f2bf(r.w);
      ub[h][4] = f2bf(s.x); ub[h][5] = f2bf(s.y); ub[h][6] = f2bf(s.z); ub[h][7] = f2bf(s.w);
    }
    *(usvec8*)&lA[ar * FBK + ac] = ua[0];
    *(usvec8*)&lA[ar * FBK + ac + 8] = ua[1];
    *(usvec8*)&lB[ar * FBK + ac] = ub[0];
    *(usvec8*)&lB[ar * FBK + ac + 8] = ub[1];
    __syncthreads();
    bf16x8 af[4], bf[4];
    #pragma unroll
    for (int m = 0; m < 4; m++)
      af[m] = *(const bf16x8*)&lA[(wr * 64 + m * 16 + (lane & 15)) * FBK + (lane >> 4) * 8];
    #pragma unroll
    for (int n = 0; n < 4; n++)
      bf[n] = *(const bf16x8*)&lB[(wc * 64 + n * 16 + (lane & 15)) * FBK + (lane >> 4) * 8];
    #pragma unroll
    for (int m = 0; m < 4; m++)
      #pragma unroll
      for (int n = 0; n < 4; n++)
        acc[m][n] = __builtin_amdgcn_mfma_f32_16x16x32_bf16(af[m], bf[n], acc[m][n], 0, 0, 0);
  }
  const int llo = lane & 15, lhi = lane >> 4;
  float cnr[4];
  int coln[4];
  #pragma unroll
  for (int n = 0; n < 4; n++) {
    coln[n] = bcol0 + wc * 64 + n * 16 + llo;
    cnr[n] = cnorm[coln[n]];
  }
  const int cslot = bcol0 / 64 + wc;
  #pragma unroll
  for (int m = 0; m < 4; m++)
    #pragma unroll
    for (int j = 0; j < 4; j++) {
      int row = brow0 + wr * 64 + m * 16 + lhi * 4 + j;
      float xn = xnorm[row];
      int lbl = labels[row];
      float rmin = 1e38f;
      #pragma unroll
      for (int n = 0; n < 4; n++) {
        float d = xn + cnr[n] - 2.0f * acc[m][n][j];
        if (coln[n] == lbl) own[row] = d;
        else rmin = fminf(rmin, d);
      }
      rmin = fminf(rmin, __shfl_xor(rmin, 1));
      rmin = fminf(rmin, __shfl_xor(rmin, 2));
      rmin = fminf(rmin, __shfl_xor(rmin, 4));
      rmin = fminf(rmin, __shfl_xor(rmin, 8));
      if (llo == 0) pmin[(size_t)row * NSLOT + cslot] = rmin;
    }
}

// ---------------- final: hinge + deterministic sum ----------------
__global__ __launch_bounds__(256) void finalize_kernel(const float* __restrict__ own,
                                                       const float* __restrict__ pmin,
                                                       const float* __restrict__ margin,
                                                       const float* __restrict__ wgt,
                                                       float* __restrict__ partial) {
  int r = blockIdx.x * 256 + threadIdx.x;
  const float4* p4 = (const float4*)(pmin + (size_t)r * NSLOT);
  float mn = 1e38f;
  #pragma unroll
  for (int i = 0; i < NSLOT / 4; i++) {
    float4 v = p4[i];
    mn = fminf(mn, fminf(fminf(v.x, v.y), fminf(v.z, v.w)));
  }
  float W = *wgt;
  float h = fmaxf(*margin + W * own[r] - (1.0f - W) * mn, 0.0f);
  #pragma unroll
  for (int m = 1; m < 64; m <<= 1) h += __shfl_xor(h, m);
  __shared__ float red[4];
  int lane = threadIdx.x & 63, wid = threadIdx.x >> 6;
  if (lane == 0) red[wid] = h;
  __syncthreads();
  if (threadIdx.x == 0) partial[blockIdx.x] = red[0] + red[1] + red[2] + red[3];
}

__global__ void final2_kernel(const float* __restrict__ partial, float* __restrict__ out) {
  float s = (threadIdx.x < NB / 256) ? partial[threadIdx.x] : 0.f;
  #pragma unroll
  for (int m = 1; m < 64; m <<= 1) s += __shfl_xor(s, m);
  if (threadIdx.x == 0) out[0] = s * (1.0f / NB);
}

extern "C" void kernel_launch(void* const* d_in, const int* in_sizes, int n_in,
                              void* d_out, int out_size, void* d_ws, size_t ws_size,
                              hipStream_t stream) {
  const float* x = (const float*)d_in[0];
  const float* cen = (const float*)d_in[1];
  const int* labels = (const int*)d_in[2];
  const float* margin = (const float*)d_in[3];
  const float* wgt = (const float*)d_in[4];
  float* out = (float*)d_out;

  char* base = (char*)d_ws;
  size_t off = 0;
  auto alloc = [&](size_t bytes) {
    void* q = base + off;
    off = (off + bytes + 255) & ~(size_t)255;
    return q;
  };
  float* xnorm = (float*)alloc((size_t)NB * 4);
  float* cnorm = (float*)alloc((size_t)NC * 4);
  float* own = (float*)alloc((size_t)NB * 4);
  float* pmin = (float*)alloc((size_t)NB * NSLOT * 4);
  float* partial = (float*)alloc(64 * 4);
  unsigned char* xb = (unsigned char*)alloc((size_t)NB * ND);
  unsigned char* cb = (unsigned char*)alloc((size_t)NC * ND);
  size_t need_big = off;  // ~27 MB

  if (ws_size >= need_big) {
    prep_kernel<<<NB + NC, 256, 0, stream>>>(x, cen, xnorm, cnorm, xb, cb);
    gemm_fp8_kernel<<<NWG, 512, 0, stream>>>(xb, cb, xnorm, cnorm, labels, own, pmin);
  } else {
    norms_kernel<<<NB + NC, 256, 0, stream>>>(x, cen, xnorm, cnorm);
    gemm_fb_kernel<<<FNWG, 256, 0, stream>>>(x, cen, xnorm, cnorm, labels, own, pmin);
  }
  finalize_kernel<<<NB / 256, 256, 0, stream>>>(own, pmin, margin, wgt, partial);
  final2_kernel<<<1, 64, 0, stream>>>(partial, out);
}

// Round 19
// 105.881 us; speedup vs baseline: 7.8775x; 7.8775x over previous
//
#include <hip/hip_runtime.h>
#include <hip/hip_bf16.h>
#include <hip/hip_fp8.h>
#include <cstdint>

// TripCenterLoss_min_margin: B=8192, C=4096, D=2048
// loss = mean_b max(margin + w*dist_own(b) - (1-w)*min_{c!=lbl} dist(b,c), 0)
// FINAL (revert to R17 = best verified: gemm ~91us, total ~106us, absmax 0.0).
// R18's cross-barrier register double-buffer spilled (WRITE_SIZE 2080KB ->
// 1.17GB scratch) -- acc(128 VGPR) + 2 frag sets don't fit; lever closed.
constexpr int NB = 8192;
constexpr int NC = 4096;
constexpr int ND = 2048;

// ---- fp8 (MX-rate) 256x256 GEMM, 16x16x128 f8f6f4, BK=128 ----
constexpr int BM = 256, BN = 256, BK = 128;
constexpr int NRB = NB / BM;    // 32
constexpr int NCB = NC / BN;    // 16
constexpr int NWG = NRB * NCB;  // 512  (%8==0 -> bijective XCD swizzle)
constexpr int NT = ND / BK;     // 16 K-tiles
constexpr int NSLOT = NC / 64;  // 64 pmin slots per row

typedef __attribute__((ext_vector_type(8))) __bf16 bf16x8;
typedef __attribute__((ext_vector_type(8))) unsigned short usvec8;
typedef __attribute__((ext_vector_type(4))) unsigned short usvec4;
typedef __attribute__((ext_vector_type(4))) float f32x4;
typedef __attribute__((ext_vector_type(4))) int i32x4;
typedef __attribute__((ext_vector_type(8))) int i32x8;

__device__ inline unsigned short f2bf(float f) {
  unsigned int u = __float_as_uint(f);
  u += 0x7fffu + ((u >> 16) & 1u);  // RNE
  return (unsigned short)(u >> 16);
}

__device__ inline unsigned char f2fp8(float f) {
  return (unsigned char)__hip_cvt_float_to_fp8(f, __HIP_SATFINITE, __HIP_E4M3);
}

// ---------------- fused norms + f32->fp8(e4m3) convert ----------------
__global__ __launch_bounds__(256) void prep_kernel(const float* __restrict__ x,
                                                   const float* __restrict__ cen,
                                                   float* __restrict__ xnorm,
                                                   float* __restrict__ cnorm,
                                                   unsigned char* __restrict__ xb,
                                                   unsigned char* __restrict__ cb) {
  int row = blockIdx.x;
  const float* src;
  float* ndst;
  unsigned char* bdst;
  if (row < NB) { src = x + (size_t)row * ND; ndst = xnorm + row; bdst = xb + (size_t)row * ND; }
  else { row -= NB; src = cen + (size_t)row * ND; ndst = cnorm + row; bdst = cb + (size_t)row * ND; }
  float s = 0.f;
  #pragma unroll
  for (int it = 0; it < 2; it++) {
    int i = threadIdx.x * 4 + it * 1024;
    float4 v = *(const float4*)(src + i);
    s += v.x * v.x + v.y * v.y + v.z * v.z + v.w * v.w;
    unsigned p = (unsigned)f2fp8(v.x) | ((unsigned)f2fp8(v.y) << 8) |
                 ((unsigned)f2fp8(v.z) << 16) | ((unsigned)f2fp8(v.w) << 24);
    *(unsigned*)(bdst + i) = p;
  }
  #pragma unroll
  for (int m = 1; m < 64; m <<= 1) s += __shfl_xor(s, m);
  __shared__ float red[4];
  int lane = threadIdx.x & 63, wid = threadIdx.x >> 6;
  if (lane == 0) red[wid] = s;
  __syncthreads();
  if (threadIdx.x == 0) *ndst = red[0] + red[1] + red[2] + red[3];
}

// ---------------- norms only (fallback path) ----------------
__global__ __launch_bounds__(256) void norms_kernel(const float* __restrict__ x,
                                                    const float* __restrict__ cen,
                                                    float* __restrict__ xnorm,
                                                    float* __restrict__ cnorm) {
  int row = blockIdx.x;
  const float* src;
  float* dst;
  if (row < NB) { src = x + (size_t)row * ND; dst = xnorm + row; }
  else          { src = cen + (size_t)(row - NB) * ND; dst = cnorm + (row - NB); }
  float s = 0.f;
  #pragma unroll
  for (int it = 0; it < 2; it++) {
    int i = threadIdx.x * 4 + it * 1024;
    float4 v = *(const float4*)(src + i);
    s += v.x * v.x + v.y * v.y + v.z * v.z + v.w * v.w;
  }
  #pragma unroll
  for (int m = 1; m < 64; m <<= 1) s += __shfl_xor(s, m);
  __shared__ float red[4];
  int lane = threadIdx.x & 63, wid = threadIdx.x >> 6;
  if (lane == 0) red[wid] = s;
  __syncthreads();
  if (threadIdx.x == 0) *dst = red[0] + red[1] + red[2] + red[3];
}

// ---------------- async global->LDS ----------------
__device__ inline void gload_lds16(const void* g, void* lds) {
  __builtin_amdgcn_global_load_lds(
      (const __attribute__((address_space(1))) unsigned int*)g,
      (__attribute__((address_space(3))) unsigned int*)lds, 16, 0, 0);
}

// ---------------- fp8 fused GEMM (R17: hoisted ptrs + m-pipeline) ----------------
// LDS [buf][A|B][256 x 128B] = 128 KiB; swizzle sx(row)=(row&7)^(((row>>3)&1)<<2)
// (6,291,456 conflict-cyc/dispatch measured = structural floor for 128B rows,
// invariant across 3 swizzles); schedule: 1 barrier/tile + vmcnt(8) ledger.
__global__ __launch_bounds__(512, 2) void gemm_fp8_kernel(
    const unsigned char* __restrict__ xb, const unsigned char* __restrict__ cb,
    const float* __restrict__ xnorm, const float* __restrict__ cnorm,
    const int* __restrict__ labels,
    float* __restrict__ own, float* __restrict__ pmin) {
  __shared__ unsigned char lds[2][2][256 * 128];  // 128 KiB

  const int tid = threadIdx.x;
  const int lane = tid & 63;
  const int wid = tid >> 6;
  const int llo = lane & 15;
  const int lkc = lane >> 4;
  const int sx = (llo & 7) ^ (((llo >> 3) & 1) << 2);  // read-side XOR term

  int bid = blockIdx.x;
  int swz = (bid & 7) * (NWG / 8) + (bid >> 3);
  const int brow0 = (swz / NCB) * BM;
  const int bcol0 = (swz % NCB) * BN;
  const int wr = wid >> 2, wc = wid & 3;  // 2x4 wave grid: wave output 128x64

  f32x4 acc[8][4];
  #pragma unroll
  for (int m = 0; m < 8; m++)
    #pragma unroll
    for (int n = 0; n < 4; n++)
      acc[m][n] = (f32x4){0.f, 0.f, 0.f, 0.f};

  // hoisted per-thread stage pointers + fixed LDS byte offsets
  const unsigned char* pga[4];
  const unsigned char* pgb[4];
  unsigned offc[4];
  #pragma unroll
  for (int i = 0; i < 4; i++) {
    int c = (wid * 4 + i) * 64 + lane;   // chunk 0..2047
    int row = c >> 3;                    // 8 chunks (128B) per row
    int sxr = (row & 7) ^ (((row >> 3) & 1) << 2);
    int kc = (c & 7) ^ sxr;              // logical chunk at this slot
    pga[i] = xb + (size_t)(brow0 + row) * ND + kc * 16;
    pgb[i] = cb + (size_t)(bcol0 + row) * ND + kc * 16;
    offc[i] = (unsigned)c * 16u;
  }
  // stage the CURRENT pointer position into buffer bf, then advance +BK
  auto stage_tile = [&](int bf) {
    #pragma unroll
    for (int i = 0; i < 4; i++) {
      gload_lds16(pga[i], &lds[bf][0][0] + offc[i]);
      gload_lds16(pgb[i], &lds[bf][1][0] + offc[i]);
    }
    #pragma unroll
    for (int i = 0; i < 4; i++) { pga[i] += BK; pgb[i] += BK; }
  };

  // precomputed read byte-offsets for the two 16B chunks of a frag
  const int cA0 = ((2 * lkc + 0) ^ sx) * 16;
  const int cA1 = ((2 * lkc + 1) ^ sx) * 16;

  auto load8 = [&](const unsigned char* p) {
    i32x4 lo = *(const i32x4*)(p + cA0);
    i32x4 hi = *(const i32x4*)(p + cA1);
    return (i32x8){lo[0], lo[1], lo[2], lo[3], hi[0], hi[1], hi[2], hi[3]};
  };

  // prologue: stage tile 0 (8 gloads/thread)
  stage_tile(0);

  for (int t = 0; t < NT; ++t) {
    const int buf = t & 1;
    __builtin_amdgcn_s_barrier();
    if (t < NT - 1) {
      stage_tile(buf ^ 1);
      asm volatile("s_waitcnt vmcnt(8)" ::: "memory");  // tile t landed
    } else {
      asm volatile("s_waitcnt vmcnt(0)" ::: "memory");
    }
    const unsigned char* Ab = &lds[buf][0][0];
    const unsigned char* Bb = &lds[buf][1][0];
    i32x8 bfr[4];
    #pragma unroll
    for (int n = 0; n < 4; n++)
      bfr[n] = load8(Bb + (wc * 64 + n * 16 + llo) * 128);
    // m-pipelined MFMA: load A(m+1) between MFMA groups of m
    i32x8 a_cur = load8(Ab + (wr * 128 + llo) * 128);
    __builtin_amdgcn_s_setprio(1);
    #pragma unroll
    for (int m = 0; m < 8; m++) {
      i32x8 a_nxt;
      if (m < 7) a_nxt = load8(Ab + (wr * 128 + (m + 1) * 16 + llo) * 128);
      #pragma unroll
      for (int n = 0; n < 4; n++)
        acc[m][n] = __builtin_amdgcn_mfma_scale_f32_16x16x128_f8f6f4(
            a_cur, bfr[n], acc[m][n], 0, 0, 0, 0x7F, 0, 0x7F);
      a_cur = a_nxt;
    }
    __builtin_amdgcn_s_setprio(0);
  }

  // ---- epilogue: dist = xn + cn - 2*dot; own-col; per-row min ----
  // C/D layout: col = lane&15, row = (lane>>4)*4 + reg  (shape-determined)
  float cnr[4];
  int coln[4];
  #pragma unroll
  for (int n = 0; n < 4; n++) {
    coln[n] = bcol0 + wc * 64 + n * 16 + llo;
    cnr[n] = cnorm[coln[n]];
  }
  const int cslot = bcol0 / 64 + wc;
  #pragma unroll
  for (int m = 0; m < 8; m++) {
    #pragma unroll
    for (int j = 0; j < 4; j++) {
      int row = brow0 + wr * 128 + m * 16 + lkc * 4 + j;
      float xn = xnorm[row];
      int lbl = labels[row];
      float rmin = 1e38f;
      #pragma unroll
      for (int n = 0; n < 4; n++) {
        float d = xn + cnr[n] - 2.0f * acc[m][n][j];
        if (coln[n] == lbl) own[row] = d;  // exactly one writer per row
        else rmin = fminf(rmin, d);
      }
      rmin = fminf(rmin, __shfl_xor(rmin, 1));
      rmin = fminf(rmin, __shfl_xor(rmin, 2));
      rmin = fminf(rmin, __shfl_xor(rmin, 4));
      rmin = fminf(rmin, __shfl_xor(rmin, 8));
      if (llo == 0) pmin[(size_t)row * NSLOT + cslot] = rmin;
    }
  }
}

// ---------------- fallback: reg-staged 128^2 fused GEMM (small ws) ----------------
constexpr int FBM = 128, FBK = 32;
constexpr int FNWG = (NB / FBM) * (NC / FBM);
__global__ __launch_bounds__(256) void gemm_fb_kernel(
    const float* __restrict__ xf, const float* __restrict__ cf,
    const float* __restrict__ xnorm, const float* __restrict__ cnorm,
    const int* __restrict__ labels,
    float* __restrict__ own, float* __restrict__ pmin) {
  __shared__ alignas(16) unsigned short lA[FBM * FBK];
  __shared__ alignas(16) unsigned short lB[FBM * FBK];
  const int tid = threadIdx.x, lane = tid & 63, wid = tid >> 6;
  int bid = blockIdx.x;
  int swz = (bid & 7) * (FNWG >> 3) + (bid >> 3);
  const int brow0 = (swz / (NC / FBM)) * FBM;
  const int bcol0 = (swz % (NC / FBM)) * FBM;
  const int wr = wid >> 1, wc = wid & 1;
  f32x4 acc[4][4];
  #pragma unroll
  for (int m = 0; m < 4; m++)
    #pragma unroll
    for (int n = 0; n < 4; n++) acc[m][n] = (f32x4){0.f, 0.f, 0.f, 0.f};
  for (int k0 = 0; k0 < ND; k0 += FBK) {
    __syncthreads();
    int ar = tid >> 1, ac = (tid & 1) << 4;
    const float* ga = xf + (size_t)(brow0 + ar) * ND + k0 + ac;
    const float* gb = cf + (size_t)(bcol0 + ar) * ND + k0 + ac;
    usvec8 ua[2], ub[2];
    #pragma unroll
    for (int h = 0; h < 2; h++) {
      float4 p = *(const float4*)(ga + h * 8), q = *(const float4*)(ga + h * 8 + 4);
      ua[h][0] = f2bf(p.x); ua[h][1] = f2bf(p.y); ua[h][2] = f2bf(p.z); ua[h][3] = f2bf(p.w);
      ua[h][4] = f2bf(q.x); ua[h][5] = f2bf(q.y); ua[h][6] = f2bf(q.z); ua[h][7] = f2bf(q.w);
      float4 r = *(const float4*)(gb + h * 8), s = *(const float4*)(gb + h * 8 + 4);
      ub[h][0] = f2bf(r.x); ub[h][1] = f2bf(r.y); ub[h][2] = f2bf(r.z); ub[h][3] = f2bf(r.w);
      ub[h][4] = f2bf(s.x); ub[h][5] = f2bf(s.y); ub[h][6] = f2bf(s.z); ub[h][7] = f2bf(s.w);
    }
    *(usvec8*)&lA[ar * FBK + ac] = ua[0];
    *(usvec8*)&lA[ar * FBK + ac + 8] = ua[1];
    *(usvec8*)&lB[ar * FBK + ac] = ub[0];
    *(usvec8*)&lB[ar * FBK + ac + 8] = ub[1];
    __syncthreads();
    bf16x8 af[4], bf[4];
    #pragma unroll
    for (int m = 0; m < 4; m++)
      af[m] = *(const bf16x8*)&lA[(wr * 64 + m * 16 + (lane & 15)) * FBK + (lane >> 4) * 8];
    #pragma unroll
    for (int n = 0; n < 4; n++)
      bf[n] = *(const bf16x8*)&lB[(wc * 64 + n * 16 + (lane & 15)) * FBK + (lane >> 4) * 8];
    #pragma unroll
    for (int m = 0; m < 4; m++)
      #pragma unroll
      for (int n = 0; n < 4; n++)
        acc[m][n] = __builtin_amdgcn_mfma_f32_16x16x32_bf16(af[m], bf[n], acc[m][n], 0, 0, 0);
  }
  const int llo = lane & 15, lhi = lane >> 4;
  float cnr[4];
  int coln[4];
  #pragma unroll
  for (int n = 0; n < 4; n++) {
    coln[n] = bcol0 + wc * 64 + n * 16 + llo;
    cnr[n] = cnorm[coln[n]];
  }
  const int cslot = bcol0 / 64 + wc;
  #pragma unroll
  for (int m = 0; m < 4; m++)
    #pragma unroll
    for (int j = 0; j < 4; j++) {
      int row = brow0 + wr * 64 + m * 16 + lhi * 4 + j;
      float xn = xnorm[row];
      int lbl = labels[row];
      float rmin = 1e38f;
      #pragma unroll
      for (int n = 0; n < 4; n++) {
        float d = xn + cnr[n] - 2.0f * acc[m][n][j];
        if (coln[n] == lbl) own[row] = d;
        else rmin = fminf(rmin, d);
      }
      rmin = fminf(rmin, __shfl_xor(rmin, 1));
      rmin = fminf(rmin, __shfl_xor(rmin, 2));
      rmin = fminf(rmin, __shfl_xor(rmin, 4));
      rmin = fminf(rmin, __shfl_xor(rmin, 8));
      if (llo == 0) pmin[(size_t)row * NSLOT + cslot] = rmin;
    }
}

// ---------------- final: hinge + deterministic sum ----------------
__global__ __launch_bounds__(256) void finalize_kernel(const float* __restrict__ own,
                                                       const float* __restrict__ pmin,
                                                       const float* __restrict__ margin,
                                                       const float* __restrict__ wgt,
                                                       float* __restrict__ partial) {
  int r = blockIdx.x * 256 + threadIdx.x;
  const float4* p4 = (const float4*)(pmin + (size_t)r * NSLOT);
  float mn = 1e38f;
  #pragma unroll
  for (int i = 0; i < NSLOT / 4; i++) {
    float4 v = p4[i];
    mn = fminf(mn, fminf(fminf(v.x, v.y), fminf(v.z, v.w)));
  }
  float W = *wgt;
  float h = fmaxf(*margin + W * own[r] - (1.0f - W) * mn, 0.0f);
  #pragma unroll
  for (int m = 1; m < 64; m <<= 1) h += __shfl_xor(h, m);
  __shared__ float red[4];
  int lane = threadIdx.x & 63, wid = threadIdx.x >> 6;
  if (lane == 0) red[wid] = h;
  __syncthreads();
  if (threadIdx.x == 0) partial[blockIdx.x] = red[0] + red[1] + red[2] + red[3];
}

__global__ void final2_kernel(const float* __restrict__ partial, float* __restrict__ out) {
  float s = (threadIdx.x < NB / 256) ? partial[threadIdx.x] : 0.f;
  #pragma unroll
  for (int m = 1; m < 64; m <<= 1) s += __shfl_xor(s, m);
  if (threadIdx.x == 0) out[0] = s * (1.0f / NB);
}

extern "C" void kernel_launch(void* const* d_in, const int* in_sizes, int n_in,
                              void* d_out, int out_size, void* d_ws, size_t ws_size,
                              hipStream_t stream) {
  const float* x = (const float*)d_in[0];
  const float* cen = (const float*)d_in[1];
  const int* labels = (const int*)d_in[2];
  const float* margin = (const float*)d_in[3];
  const float* wgt = (const float*)d_in[4];
  float* out = (float*)d_out;

  char* base = (char*)d_ws;
  size_t off = 0;
  auto alloc = [&](size_t bytes) {
    void* q = base + off;
    off = (off + bytes + 255) & ~(size_t)255;
    return q;
  };
  float* xnorm = (float*)alloc((size_t)NB * 4);
  float* cnorm = (float*)alloc((size_t)NC * 4);
  float* own = (float*)alloc((size_t)NB * 4);
  float* pmin = (float*)alloc((size_t)NB * NSLOT * 4);
  float* partial = (float*)alloc(64 * 4);
  unsigned char* xb = (unsigned char*)alloc((size_t)NB * ND);
  unsigned char* cb = (unsigned char*)alloc((size_t)NC * ND);
  size_t need_big = off;  // ~27 MB

  if (ws_size >= need_big) {
    prep_kernel<<<NB + NC, 256, 0, stream>>>(x, cen, xnorm, cnorm, xb, cb);
    gemm_fp8_kernel<<<NWG, 512, 0, stream>>>(xb, cb, xnorm, cnorm, labels, own, pmin);
  } else {
    norms_kernel<<<NB + NC, 256, 0, stream>>>(x, cen, xnorm, cnorm);
    gemm_fb_kernel<<<FNWG, 256, 0, stream>>>(x, cen, xnorm, cnorm, labels, own, pmin);
  }
  finalize_kernel<<<NB / 256, 256, 0, stream>>>(own, pmin, margin, wgt, partial);
  final2_kernel<<<1, 64, 0, stream>>>(partial, out);
}